// Round 10
// baseline (569.653 us; speedup 1.0000x reference)
//
#include <hip/hip_runtime.h>
#include <hip/hip_bf16.h>

#define MCH 256
#define TT 16384
#define KW 64
#define LOUT (TT - KW + 1)   // 16321

typedef float f32x4 __attribute__((ext_vector_type(4)));
typedef int   i32x4 __attribute__((ext_vector_type(4)));

// Workspace layout
#define XT_ROWS 16448
#define Y_BYTES  ((size_t)MCH * LOUT * 4)          // 16,712,704
#define AW_I8    ((size_t)16 * 524288)             // 8,388,608
#define XT_I8    ((size_t)XT_ROWS * 512)           // 8,421,376

// Fixed-point split: x = X1/16 + X2/4096, w = W1/512 + W2/131072 (i8 limbs).
// Kept products: hh (1/8192), hl+lh (1/2097152, shared acc). Dropped ll.

// ---- W quant: w[o][i][tap] fp32 -> aw[og16][tap64][chunk4][limb2][o16][ch64] i8
__global__ __launch_bounds__(256)
void w_quant(const float* __restrict__ w, char* __restrict__ aw)
{
    __shared__ float lw[64 * 65];   // [tap][i], pad 65
    const int b = blockIdx.x;       // o*4 + c
    const int o = b >> 2;
    const int c = b & 3;
    const int tid = threadIdx.x;

    const float4* wb = reinterpret_cast<const float4*>(w + ((size_t)o * 256 + c * 64) * 64);
#pragma unroll
    for (int s = 0; s < 4; ++s) {
        int u = s * 256 + tid;      // 0..1023
        float4 v = wb[u];
        int il = u >> 4, tq = u & 15;
#pragma unroll
        for (int j = 0; j < 4; ++j)
            lw[(tq * 4 + j) * 65 + il] = (&v.x)[j];
    }
    __syncthreads();

    const int tap = tid >> 2;
    const int g   = tid & 3;
    alignas(16) char b1[16], b2[16];
    const float* src = lw + tap * 65 + g * 16;
#pragma unroll
    for (int j = 0; j < 16; ++j) {
        float v = src[j];
        int q1 = __float2int_rn(v * 512.f);
        q1 = max(-127, min(127, q1));
        float r = v - q1 * (1.f / 512.f);
        int q2 = __float2int_rn(r * 131072.f);
        q2 = max(-127, min(127, q2));
        b1[j] = (char)q1;
        b2[j] = (char)q2;
    }
    size_t base = (size_t)(o >> 4) * 524288 + (size_t)tap * 8192 + c * 2048
                + (o & 15) * 64 + g * 16;
    *reinterpret_cast<i32x4*>(aw + base)        = *reinterpret_cast<const i32x4*>(b1);
    *reinterpret_cast<i32x4*>(aw + base + 1024) = *reinterpret_cast<const i32x4*>(b2);
}

// ---- X quant: x[i][t] fp32 -> xt[t][chunk4][limb2][ch64] i8 (rows >= TT zero)
__global__ __launch_bounds__(256)
void x_quant(const float* __restrict__ x, char* __restrict__ xt)
{
    __shared__ float lx[128 * 65];  // [t_loc][i], pad 65
    const int tb = blockIdx.x;      // 0..128
    const int c  = blockIdx.y;
    const int tid = threadIdx.x;
    const int t0 = tb * 128;

#pragma unroll
    for (int s = 0; s < 8; ++s) {
        int u = s * 256 + tid;      // 0..2047
        int il = u >> 5, tq = u & 31;
        float4 v = {0.f, 0.f, 0.f, 0.f};
        if (t0 < TT)
            v = *reinterpret_cast<const float4*>(x + (size_t)(c * 64 + il) * TT + t0 + tq * 4);
#pragma unroll
        for (int j = 0; j < 4; ++j)
            lx[(tq * 4 + j) * 65 + il] = (&v.x)[j];
    }
    __syncthreads();

    const int tl = tid >> 1;
    const int h  = tid & 1;
    const int t  = t0 + tl;
    alignas(16) char b1[32], b2[32];
    const float* src = lx + tl * 65 + h * 32;
#pragma unroll
    for (int k = 0; k < 32; ++k) {
        float v = src[k];
        int q1 = __float2int_rn(v * 16.f);
        q1 = max(-127, min(127, q1));
        float r = v - q1 * 0.0625f;
        int q2 = __float2int_rn(r * 4096.f);
        q2 = max(-127, min(127, q2));
        b1[k] = (char)q1;
        b2[k] = (char)q2;
    }
    if (t < XT_ROWS) {
        char* dst = xt + (size_t)t * 512 + c * 128 + h * 32;
        *reinterpret_cast<i32x4*>(dst)           = *reinterpret_cast<const i32x4*>(b1);
        *reinterpret_cast<i32x4*>(dst + 16)      = *reinterpret_cast<const i32x4*>(b1 + 16);
        *reinterpret_cast<i32x4*>(dst + 64)      = *reinterpret_cast<const i32x4*>(b2);
        *reinterpret_cast<i32x4*>(dst + 64 + 16) = *reinterpret_cast<const i32x4*>(b2 + 16);
    }
}

// ---- i8 MFMA conv: block = 64o x 64l, 4 waves (16o x 64l each), 4 c-chunks.
// Grid 1024 -> 4 blocks/CU -> 4 waves/SIMD (occupancy lever, round-6 geometry).
// Per kt: 14 ds_read_b128 (7 conv-reuse row-groups x 2 limbs) -> 48 MFMAs.

#define PREFI(dst, c_, kt_) do {                                             \
    const char* _ap = Abase + (size_t)(kt_) * 8192 + (c_) * 2048;            \
    _Pragma("unroll")                                                        \
    for (int _kb = 0; _kb < 4; ++_kb) {                                      \
        dst[_kb * 2 + 0] = *reinterpret_cast<const i32x4*>(_ap + _kb * 131072);        \
        dst[_kb * 2 + 1] = *reinterpret_cast<const i32x4*>(_ap + _kb * 131072 + 1024); \
    }                                                                        \
} while (0)

#define READBH(Br_, kt_) do {                                                \
    _Pragma("unroll")                                                        \
    for (int _q = 0; _q < 7; ++_q) {                                         \
        int _r = lr + (kt_) + _q * 16;                                       \
        int _s0 = (g ^ (_r & 7)) << 4;                                       \
        bH[_q] = *reinterpret_cast<const i32x4*>((Br_) + _r * 128 + _s0);    \
    }                                                                        \
} while (0)

#define READBL(Br_, kt_) do {                                                \
    _Pragma("unroll")                                                        \
    for (int _q = 0; _q < 7; ++_q) {                                         \
        int _r = lr + (kt_) + _q * 16;                                       \
        int _s0 = (g ^ (_r & 7)) << 4;                                       \
        bL[_q] = *reinterpret_cast<const i32x4*>((Br_) + _r * 128 + (_s0 ^ 64)); \
    }                                                                        \
} while (0)

// bH products (accH += a0*bH, accM += a1*bH): 32 MFMAs.
#define COMPH(a_) do {                                                       \
    _Pragma("unroll")                                                        \
    for (int _kb = 0; _kb < 4; ++_kb)                                        \
    { _Pragma("unroll")                                                      \
      for (int _cf = 0; _cf < 4; ++_cf)                                      \
        asm volatile("v_mfma_i32_16x16x64_i8 %0, %1, %2, %0"                 \
            : "+v"(accH[_cf]) : "v"(a_[_kb*2+0]), "v"(bH[_cf+_kb])); }       \
    _Pragma("unroll")                                                        \
    for (int _kb = 0; _kb < 4; ++_kb)                                        \
    { _Pragma("unroll")                                                      \
      for (int _cf = 0; _cf < 4; ++_cf)                                      \
        asm volatile("v_mfma_i32_16x16x64_i8 %0, %1, %2, %0"                 \
            : "+v"(accM[_cf]) : "v"(a_[_kb*2+1]), "v"(bH[_cf+_kb])); }       \
} while (0)

// bL product (accM += a0*bL): 16 MFMAs.
#define COMPL(a_) do {                                                       \
    _Pragma("unroll")                                                        \
    for (int _kb = 0; _kb < 4; ++_kb)                                        \
    { _Pragma("unroll")                                                      \
      for (int _cf = 0; _cf < 4; ++_cf)                                      \
        asm volatile("v_mfma_i32_16x16x64_i8 %0, %1, %2, %0"                 \
            : "+v"(accM[_cf]) : "v"(a_[_kb*2+0]), "v"(bL[_cf+_kb])); }       \
} while (0)

#define SLOAD(c_) do {                                                       \
    _Pragma("unroll")                                                        \
    for (int _s = 0; _s < 4; ++_s) {                                         \
        int _u = _s * 256 + tid;                                             \
        int _row = _u >> 3, _un = _u & 7;                                    \
        stg[_s] = *reinterpret_cast<const i32x4*>(                           \
            xt + (size_t)(l0 + _row) * 512 + (c_) * 128 + _un * 16);         \
    }                                                                        \
} while (0)

#define SWRITE(buf_) do {                                                    \
    _Pragma("unroll")                                                        \
    for (int _s = 0; _s < 4; ++_s) {                                         \
        int _u = _s * 256 + tid;                                             \
        int _row = _u >> 3, _un = _u & 7;                                    \
        *reinterpret_cast<i32x4*>((buf_) + _row * 128 +                      \
            ((_un ^ (_row & 7)) << 4)) = stg[_s];                            \
    }                                                                        \
} while (0)

__global__ __launch_bounds__(256, 4)
void conv_i8(const char* __restrict__ aw, const char* __restrict__ xt,
             const float* __restrict__ bias, float* __restrict__ y)
{
    __shared__ char Bs[2][128 * 128];   // 32 KB total

    const int tid  = threadIdx.x;
    const int lane = tid & 63;
    const int wv   = tid >> 6;
    const int id   = blockIdx.x;            // 0..1023
    const int og   = (id & 7) >> 1;         // XCD-locality: 2 MB A slice per XCD L2
    const int lblk = (id >> 3) * 2 + (id & 1);
    const int l0   = lblk * 64;
    const int lr   = lane & 15;
    const int g    = lane >> 4;

    i32x4 accH[4], accM[4];
#pragma unroll
    for (int i = 0; i < 4; ++i) {
        accH[i] = (i32x4){0, 0, 0, 0};
        accM[i] = (i32x4){0, 0, 0, 0};
    }

    const char* Abase = aw + (size_t)(og * 4 + wv) * 524288 + lr * 64 + g * 16;

    i32x4 aP[8], aQ[8], stg[4];
    i32x4 bH[7], bL[7];

    SLOAD(0);
    PREFI(aP, 0, 0);
    SWRITE(Bs[0]);
    __syncthreads();

    for (int c = 0; c < 4; ++c) {
        if (c < 3) SLOAD(c + 1);
        char* Br = Bs[c & 1];

        for (int ktt = 0; ktt < 16; ktt += 2) {
            PREFI(aQ, c, ktt + 1);
            READBH(Br, ktt);
            READBL(Br, ktt);
            COMPH(aP);
            COMPL(aP);
            if (ktt < 14)      PREFI(aP, c, ktt + 2);
            else if (c < 3)    PREFI(aP, c + 1, 0);
            READBH(Br, ktt + 1);
            READBL(Br, ktt + 1);
            COMPH(aQ);
            COMPL(aQ);
        }

        if (c < 3) {
            SWRITE(Bs[(c + 1) & 1]);
            __syncthreads();
        }
    }

    asm volatile("s_nop 7\n\ts_nop 7" :::);   // MFMA -> VALU hazard guard

    const int obase = og * 64 + wv * 16 + g * 4;
#pragma unroll
    for (int r = 0; r < 4; ++r) {
        int o = obase + r;
        float bv = bias[o];
#pragma unroll
        for (int cf = 0; cf < 4; ++cf) {
            int ll = l0 + cf * 16 + lr;
            if (ll < LOUT) {
                int hA = accH[cf][r];
                int hi = hA >> 12;          // hA = hi*4096 + lo, both exact in f32
                int lo = hA & 4095;
                float v = (float)hi * 0.5f
                        + (float)lo * (1.f / 8192.f)
                        + (float)accM[cf][r] * (1.f / 2097152.f)
                        + bv;
                y[(size_t)o * LOUT + ll] = v;
            }
        }
    }
}

// ---- chunked-parallel tanh scan ----
#define CHUNK 64
#define WARM 32
#define NCHUNK 256

static __device__ __forceinline__ float fast_tanh(float z) {
    float e = __expf(2.f * z);
    return 1.f - 2.f / (e + 1.f);
}

__global__ void scan_kernel(const float* __restrict__ y,
                            const float* __restrict__ pw,
                            float* __restrict__ out)
{
    int t = blockIdx.x * blockDim.x + threadIdx.x;   // 256*256
    int m = t >> 8;
    int c = t & (NCHUNK - 1);
    float w = pw[m];
    const float* ym = y + (size_t)m * LOUT;
    float* om = out + (size_t)m * (LOUT + 1);
    float pos;
    int l;
    if (c == 0) {
        om[0] = -1.f;
        pos = -1.f;
        l = 0;
    } else {
        pos = 0.f;
        l = c * CHUNK - WARM;
        int s = c * CHUNK;
#pragma unroll 4
        for (; l < s; ++l)
            pos = fast_tanh(fmaf(pos, w, ym[l]));
    }
    int e = min((c + 1) * CHUNK, LOUT);
#pragma unroll 4
    for (; l < e; ++l) {
        pos = fast_tanh(fmaf(pos, w, ym[l]));
        om[l + 1] = pos;
    }
}

extern "C" void kernel_launch(void* const* d_in, const int* in_sizes, int n_in,
                              void* d_out, int out_size, void* d_ws, size_t ws_size,
                              hipStream_t stream) {
    const float* x  = (const float*)d_in[0];
    const float* cw = (const float*)d_in[1];
    const float* cb = (const float*)d_in[2];
    const float* pw = (const float*)d_in[3];
    float* out = (float*)d_out;

    float* y  = (float*)d_ws;
    char*  aw = (char*)d_ws + Y_BYTES;
    char*  xt = (char*)d_ws + Y_BYTES + AW_I8;

    w_quant<<<1024, 256, 0, stream>>>(cw, aw);
    dim3 xgrid(129, 4);
    x_quant<<<xgrid, 256, 0, stream>>>(x, xt);
    conv_i8<<<1024, 256, 0, stream>>>(aw, xt, cb, y);
    scan_kernel<<<256, 256, 0, stream>>>(y, pw, out);
}

// Round 11
// 196.504 us; speedup vs baseline: 2.8989x; 2.8989x over previous
//
#include <hip/hip_runtime.h>
#include <hip/hip_bf16.h>

#define MCH 256
#define TT 16384
#define KW 64
#define LOUT (TT - KW + 1)   // 16321

typedef float f32x4 __attribute__((ext_vector_type(4)));
typedef int   i32x4 __attribute__((ext_vector_type(4)));

// Workspace layout
#define XT_ROWS 16448
#define Y_BYTES  ((size_t)MCH * LOUT * 4)          // 16,712,704
#define AW_I8    ((size_t)16 * 524288)             // 8,388,608
#define XT_I8    ((size_t)XT_ROWS * 512)           // 8,421,376

// Fixed-point split: x = X1/16 + X2/4096, w = W1/512 + W2/131072 (i8 limbs).
// Kept products: hh (1/8192), hl+lh (1/2097152, shared acc). Dropped ll.

// ---- W quant: w[o][i][tap] fp32 -> aw[og16][tap64][chunk4][limb2][o16][ch64] i8
__global__ __launch_bounds__(256)
void w_quant(const float* __restrict__ w, char* __restrict__ aw)
{
    __shared__ float lw[64 * 65];   // [tap][i], pad 65
    const int b = blockIdx.x;       // o*4 + c
    const int o = b >> 2;
    const int c = b & 3;
    const int tid = threadIdx.x;

    const float4* wb = reinterpret_cast<const float4*>(w + ((size_t)o * 256 + c * 64) * 64);
#pragma unroll
    for (int s = 0; s < 4; ++s) {
        int u = s * 256 + tid;      // 0..1023
        float4 v = wb[u];
        int il = u >> 4, tq = u & 15;
#pragma unroll
        for (int j = 0; j < 4; ++j)
            lw[(tq * 4 + j) * 65 + il] = (&v.x)[j];
    }
    __syncthreads();

    const int tap = tid >> 2;
    const int g   = tid & 3;
    alignas(16) char b1[16], b2[16];
    const float* src = lw + tap * 65 + g * 16;
#pragma unroll
    for (int j = 0; j < 16; ++j) {
        float v = src[j];
        int q1 = __float2int_rn(v * 512.f);
        q1 = max(-127, min(127, q1));
        float r = v - q1 * (1.f / 512.f);
        int q2 = __float2int_rn(r * 131072.f);
        q2 = max(-127, min(127, q2));
        b1[j] = (char)q1;
        b2[j] = (char)q2;
    }
    size_t base = (size_t)(o >> 4) * 524288 + (size_t)tap * 8192 + c * 2048
                + (o & 15) * 64 + g * 16;
    *reinterpret_cast<i32x4*>(aw + base)        = *reinterpret_cast<const i32x4*>(b1);
    *reinterpret_cast<i32x4*>(aw + base + 1024) = *reinterpret_cast<const i32x4*>(b2);
}

// ---- X quant: x[i][t] fp32 -> xt[t][chunk4][limb2][ch64] i8 (rows >= TT zero)
__global__ __launch_bounds__(256)
void x_quant(const float* __restrict__ x, char* __restrict__ xt)
{
    __shared__ float lx[128 * 65];  // [t_loc][i], pad 65
    const int tb = blockIdx.x;      // 0..128
    const int c  = blockIdx.y;
    const int tid = threadIdx.x;
    const int t0 = tb * 128;

#pragma unroll
    for (int s = 0; s < 8; ++s) {
        int u = s * 256 + tid;      // 0..2047
        int il = u >> 5, tq = u & 31;
        float4 v = {0.f, 0.f, 0.f, 0.f};
        if (t0 < TT)
            v = *reinterpret_cast<const float4*>(x + (size_t)(c * 64 + il) * TT + t0 + tq * 4);
#pragma unroll
        for (int j = 0; j < 4; ++j)
            lx[(tq * 4 + j) * 65 + il] = (&v.x)[j];
    }
    __syncthreads();

    const int tl = tid >> 1;
    const int h  = tid & 1;
    const int t  = t0 + tl;
    alignas(16) char b1[32], b2[32];
    const float* src = lx + tl * 65 + h * 32;
#pragma unroll
    for (int k = 0; k < 32; ++k) {
        float v = src[k];
        int q1 = __float2int_rn(v * 16.f);
        q1 = max(-127, min(127, q1));
        float r = v - q1 * 0.0625f;
        int q2 = __float2int_rn(r * 4096.f);
        q2 = max(-127, min(127, q2));
        b1[k] = (char)q1;
        b2[k] = (char)q2;
    }
    if (t < XT_ROWS) {
        char* dst = xt + (size_t)t * 512 + c * 128 + h * 32;
        *reinterpret_cast<i32x4*>(dst)           = *reinterpret_cast<const i32x4*>(b1);
        *reinterpret_cast<i32x4*>(dst + 16)      = *reinterpret_cast<const i32x4*>(b1 + 16);
        *reinterpret_cast<i32x4*>(dst + 64)      = *reinterpret_cast<const i32x4*>(b2);
        *reinterpret_cast<i32x4*>(dst + 64 + 16) = *reinterpret_cast<const i32x4*>(b2 + 16);
    }
}

// ---- i8 MFMA conv: block = 64o x 64l, 4 waves (16o x 64l each), 4 c-chunks.
// Round-6 geometry (proven 74% of floor), 3-product numerics (rounds 7-9),
// launch_bounds(256,2): no register cap -> no scratch spill (round-10 lesson).
// Per kt: 14 ds_read_b128 (7 conv-reuse row-groups x 2 limbs) -> 48 MFMAs.

#define PREFI(dst, c_, kt_) do {                                             \
    const char* _ap = Abase + (size_t)(kt_) * 8192 + (c_) * 2048;            \
    _Pragma("unroll")                                                        \
    for (int _kb = 0; _kb < 4; ++_kb) {                                      \
        dst[_kb * 2 + 0] = *reinterpret_cast<const i32x4*>(_ap + _kb * 131072);        \
        dst[_kb * 2 + 1] = *reinterpret_cast<const i32x4*>(_ap + _kb * 131072 + 1024); \
    }                                                                        \
} while (0)

#define READBH(Br_, kt_) do {                                                \
    _Pragma("unroll")                                                        \
    for (int _q = 0; _q < 7; ++_q) {                                         \
        int _r = lr + (kt_) + _q * 16;                                       \
        int _s0 = (g ^ (_r & 7)) << 4;                                       \
        bH[_q] = *reinterpret_cast<const i32x4*>((Br_) + _r * 128 + _s0);    \
    }                                                                        \
} while (0)

#define READBL(Br_, kt_) do {                                                \
    _Pragma("unroll")                                                        \
    for (int _q = 0; _q < 7; ++_q) {                                         \
        int _r = lr + (kt_) + _q * 16;                                       \
        int _s0 = (g ^ (_r & 7)) << 4;                                       \
        bL[_q] = *reinterpret_cast<const i32x4*>((Br_) + _r * 128 + (_s0 ^ 64)); \
    }                                                                        \
} while (0)

// bH products (accH += a0*bH, accM += a1*bH): 32 MFMAs.
#define COMPH(a_) do {                                                       \
    _Pragma("unroll")                                                        \
    for (int _kb = 0; _kb < 4; ++_kb)                                        \
    { _Pragma("unroll")                                                      \
      for (int _cf = 0; _cf < 4; ++_cf)                                      \
        asm volatile("v_mfma_i32_16x16x64_i8 %0, %1, %2, %0"                 \
            : "+v"(accH[_cf]) : "v"(a_[_kb*2+0]), "v"(bH[_cf+_kb])); }       \
    _Pragma("unroll")                                                        \
    for (int _kb = 0; _kb < 4; ++_kb)                                        \
    { _Pragma("unroll")                                                      \
      for (int _cf = 0; _cf < 4; ++_cf)                                      \
        asm volatile("v_mfma_i32_16x16x64_i8 %0, %1, %2, %0"                 \
            : "+v"(accM[_cf]) : "v"(a_[_kb*2+1]), "v"(bH[_cf+_kb])); }       \
} while (0)

// bL product (accM += a0*bL): 16 MFMAs.
#define COMPL(a_) do {                                                       \
    _Pragma("unroll")                                                        \
    for (int _kb = 0; _kb < 4; ++_kb)                                        \
    { _Pragma("unroll")                                                      \
      for (int _cf = 0; _cf < 4; ++_cf)                                      \
        asm volatile("v_mfma_i32_16x16x64_i8 %0, %1, %2, %0"                 \
            : "+v"(accM[_cf]) : "v"(a_[_kb*2+0]), "v"(bL[_cf+_kb])); }       \
} while (0)

#define SLOAD(c_) do {                                                       \
    _Pragma("unroll")                                                        \
    for (int _s = 0; _s < 4; ++_s) {                                         \
        int _u = _s * 256 + tid;                                             \
        int _row = _u >> 3, _un = _u & 7;                                    \
        stg[_s] = *reinterpret_cast<const i32x4*>(                           \
            xt + (size_t)(l0 + _row) * 512 + (c_) * 128 + _un * 16);         \
    }                                                                        \
} while (0)

#define SWRITE(buf_) do {                                                    \
    _Pragma("unroll")                                                        \
    for (int _s = 0; _s < 4; ++_s) {                                         \
        int _u = _s * 256 + tid;                                             \
        int _row = _u >> 3, _un = _u & 7;                                    \
        *reinterpret_cast<i32x4*>((buf_) + _row * 128 +                      \
            ((_un ^ (_row & 7)) << 4)) = stg[_s];                            \
    }                                                                        \
} while (0)

__global__ __launch_bounds__(256, 2)
void conv_i8(const char* __restrict__ aw, const char* __restrict__ xt,
             const float* __restrict__ bias, float* __restrict__ y)
{
    __shared__ char Bs[2][128 * 128];   // 32 KB total

    const int tid  = threadIdx.x;
    const int lane = tid & 63;
    const int wv   = tid >> 6;
    const int id   = blockIdx.x;            // 0..1023
    const int og   = (id & 7) >> 1;         // XCD-locality: 2 MB A slice per XCD L2
    const int lblk = (id >> 3) * 2 + (id & 1);
    const int l0   = lblk * 64;
    const int lr   = lane & 15;
    const int g    = lane >> 4;

    i32x4 accH[4], accM[4];
#pragma unroll
    for (int i = 0; i < 4; ++i) {
        accH[i] = (i32x4){0, 0, 0, 0};
        accM[i] = (i32x4){0, 0, 0, 0};
    }

    const char* Abase = aw + (size_t)(og * 4 + wv) * 524288 + lr * 64 + g * 16;

    i32x4 aP[8], aQ[8], stg[4];
    i32x4 bH[7], bL[7];

    SLOAD(0);
    PREFI(aP, 0, 0);
    SWRITE(Bs[0]);
    __syncthreads();

    for (int c = 0; c < 4; ++c) {
        if (c < 3) SLOAD(c + 1);
        char* Br = Bs[c & 1];

        for (int ktt = 0; ktt < 16; ktt += 2) {
            PREFI(aQ, c, ktt + 1);
            READBH(Br, ktt);
            READBL(Br, ktt);
            COMPH(aP);
            COMPL(aP);
            if (ktt < 14)      PREFI(aP, c, ktt + 2);
            else if (c < 3)    PREFI(aP, c + 1, 0);
            READBH(Br, ktt + 1);
            READBL(Br, ktt + 1);
            COMPH(aQ);
            COMPL(aQ);
        }

        if (c < 3) {
            SWRITE(Bs[(c + 1) & 1]);
            __syncthreads();
        }
    }

    asm volatile("s_nop 7\n\ts_nop 7" :::);   // MFMA -> VALU hazard guard

    const int obase = og * 64 + wv * 16 + g * 4;
#pragma unroll
    for (int r = 0; r < 4; ++r) {
        int o = obase + r;
        float bv = bias[o];
#pragma unroll
        for (int cf = 0; cf < 4; ++cf) {
            int ll = l0 + cf * 16 + lr;
            if (ll < LOUT) {
                int hA = accH[cf][r];
                int hi = hA >> 12;          // hA = hi*4096 + lo, both exact in f32
                int lo = hA & 4095;
                float v = (float)hi * 0.5f
                        + (float)lo * (1.f / 8192.f)
                        + (float)accM[cf][r] * (1.f / 2097152.f)
                        + bv;
                y[(size_t)o * LOUT + ll] = v;
            }
        }
    }
}

// ---- chunked-parallel tanh scan ----
#define CHUNK 64
#define WARM 32
#define NCHUNK 256

static __device__ __forceinline__ float fast_tanh(float z) {
    float e = __expf(2.f * z);
    return 1.f - 2.f / (e + 1.f);
}

__global__ void scan_kernel(const float* __restrict__ y,
                            const float* __restrict__ pw,
                            float* __restrict__ out)
{
    int t = blockIdx.x * blockDim.x + threadIdx.x;   // 256*256
    int m = t >> 8;
    int c = t & (NCHUNK - 1);
    float w = pw[m];
    const float* ym = y + (size_t)m * LOUT;
    float* om = out + (size_t)m * (LOUT + 1);
    float pos;
    int l;
    if (c == 0) {
        om[0] = -1.f;
        pos = -1.f;
        l = 0;
    } else {
        pos = 0.f;
        l = c * CHUNK - WARM;
        int s = c * CHUNK;
#pragma unroll 4
        for (; l < s; ++l)
            pos = fast_tanh(fmaf(pos, w, ym[l]));
    }
    int e = min((c + 1) * CHUNK, LOUT);
#pragma unroll 4
    for (; l < e; ++l) {
        pos = fast_tanh(fmaf(pos, w, ym[l]));
        om[l + 1] = pos;
    }
}

extern "C" void kernel_launch(void* const* d_in, const int* in_sizes, int n_in,
                              void* d_out, int out_size, void* d_ws, size_t ws_size,
                              hipStream_t stream) {
    const float* x  = (const float*)d_in[0];
    const float* cw = (const float*)d_in[1];
    const float* cb = (const float*)d_in[2];
    const float* pw = (const float*)d_in[3];
    float* out = (float*)d_out;

    float* y  = (float*)d_ws;
    char*  aw = (char*)d_ws + Y_BYTES;
    char*  xt = (char*)d_ws + Y_BYTES + AW_I8;

    w_quant<<<1024, 256, 0, stream>>>(cw, aw);
    dim3 xgrid(129, 4);
    x_quant<<<xgrid, 256, 0, stream>>>(x, xt);
    conv_i8<<<1024, 256, 0, stream>>>(aw, xt, cb, y);
    scan_kernel<<<256, 256, 0, stream>>>(y, pw, out);
}

// Round 12
// 174.333 us; speedup vs baseline: 3.2676x; 1.1272x over previous
//
#include <hip/hip_runtime.h>
#include <hip/hip_bf16.h>

#define MCH 256
#define TT 16384
#define KW 64
#define LOUT (TT - KW + 1)   // 16321

typedef float f32x4 __attribute__((ext_vector_type(4)));
typedef int   i32x4 __attribute__((ext_vector_type(4)));

// Workspace layout
#define XT_ROWS 16448
#define Y_BYTES  ((size_t)MCH * LOUT * 4)          // 16,712,704
#define AW_I8    ((size_t)16 * 524288)             // 8,388,608
#define XT_I8    ((size_t)XT_ROWS * 512)           // 8,421,376

// Fixed-point split: x = X1/16 + X2/4096, w = W1/512 + W2/131072 (i8 limbs).
// Kept products: hh (1/8192), hl+lh (1/2097152, shared acc). Dropped ll.

// ---- Fused quantization: blocks 0..1023 -> W path, 1024..1539 -> X path.
__global__ __launch_bounds__(256)
void quant_fused(const float* __restrict__ w, const float* __restrict__ x,
                 char* __restrict__ aw, char* __restrict__ xt)
{
    __shared__ float ls[128 * 65];
    const int tid = threadIdx.x;
    const int b = blockIdx.x;

    if (b < 1024) {
        // ---- W path: w[o][i][tap] -> aw[og16][tap64][chunk4][limb2][o16][ch64]
        const int o = b >> 2;
        const int c = b & 3;
        const float4* wb = reinterpret_cast<const float4*>(w + ((size_t)o * 256 + c * 64) * 64);
#pragma unroll
        for (int s = 0; s < 4; ++s) {
            int u = s * 256 + tid;      // 0..1023
            float4 v = wb[u];
            int il = u >> 4, tq = u & 15;
#pragma unroll
            for (int j = 0; j < 4; ++j)
                ls[(tq * 4 + j) * 65 + il] = (&v.x)[j];
        }
        __syncthreads();

        const int tap = tid >> 2;
        const int g   = tid & 3;
        alignas(16) char b1[16], b2[16];
        const float* src = ls + tap * 65 + g * 16;
#pragma unroll
        for (int j = 0; j < 16; ++j) {
            float v = src[j];
            int q1 = __float2int_rn(v * 512.f);
            q1 = max(-127, min(127, q1));
            float r = v - q1 * (1.f / 512.f);
            int q2 = __float2int_rn(r * 131072.f);
            q2 = max(-127, min(127, q2));
            b1[j] = (char)q1;
            b2[j] = (char)q2;
        }
        size_t base = (size_t)(o >> 4) * 524288 + (size_t)tap * 8192 + c * 2048
                    + (o & 15) * 64 + g * 16;
        *reinterpret_cast<i32x4*>(aw + base)        = *reinterpret_cast<const i32x4*>(b1);
        *reinterpret_cast<i32x4*>(aw + base + 1024) = *reinterpret_cast<const i32x4*>(b2);
    } else {
        // ---- X path: x[i][t] -> xt[t][chunk4][limb2][ch64] (rows >= TT zero)
        const int bb = b - 1024;        // 0..515
        const int tb = bb % 129;
        const int c  = bb / 129;
        const int t0 = tb * 128;

#pragma unroll
        for (int s = 0; s < 8; ++s) {
            int u = s * 256 + tid;      // 0..2047
            int il = u >> 5, tq = u & 31;
            float4 v = {0.f, 0.f, 0.f, 0.f};
            if (t0 < TT)
                v = *reinterpret_cast<const float4*>(x + (size_t)(c * 64 + il) * TT + t0 + tq * 4);
#pragma unroll
            for (int j = 0; j < 4; ++j)
                ls[(tq * 4 + j) * 65 + il] = (&v.x)[j];
        }
        __syncthreads();

        const int tl = tid >> 1;
        const int h  = tid & 1;
        const int t  = t0 + tl;
        alignas(16) char b1[32], b2[32];
        const float* src = ls + tl * 65 + h * 32;
#pragma unroll
        for (int k = 0; k < 32; ++k) {
            float v = src[k];
            int q1 = __float2int_rn(v * 16.f);
            q1 = max(-127, min(127, q1));
            float r = v - q1 * 0.0625f;
            int q2 = __float2int_rn(r * 4096.f);
            q2 = max(-127, min(127, q2));
            b1[k] = (char)q1;
            b2[k] = (char)q2;
        }
        if (t < XT_ROWS) {
            char* dst = xt + (size_t)t * 512 + c * 128 + h * 32;
            *reinterpret_cast<i32x4*>(dst)           = *reinterpret_cast<const i32x4*>(b1);
            *reinterpret_cast<i32x4*>(dst + 16)      = *reinterpret_cast<const i32x4*>(b1 + 16);
            *reinterpret_cast<i32x4*>(dst + 64)      = *reinterpret_cast<const i32x4*>(b2);
            *reinterpret_cast<i32x4*>(dst + 64 + 16) = *reinterpret_cast<const i32x4*>(b2 + 16);
        }
    }
}

// ---- i8 MFMA conv (round-9 exact): block = 64o x 128l, 4 waves, 4 c-chunks.
// Per kt: 22 ds_read_b128 (11 conv-reuse row-groups x 2 limbs) -> 96 MFMAs.

#define PREFI(dst, c_, kt_) do {                                             \
    const char* _ap = Abase + (size_t)(kt_) * 8192 + (c_) * 2048;            \
    _Pragma("unroll")                                                        \
    for (int _kb = 0; _kb < 4; ++_kb) {                                      \
        dst[_kb * 2 + 0] = *reinterpret_cast<const i32x4*>(_ap + _kb * 131072);        \
        dst[_kb * 2 + 1] = *reinterpret_cast<const i32x4*>(_ap + _kb * 131072 + 1024); \
    }                                                                        \
} while (0)

#define READBH(Br_, kt_) do {                                                \
    _Pragma("unroll")                                                        \
    for (int _q = 0; _q < 11; ++_q) {                                        \
        int _r = lr + (kt_) + _q * 16;                                       \
        int _s0 = (g ^ (_r & 7)) << 4;                                       \
        bH[_q] = *reinterpret_cast<const i32x4*>((Br_) + _r * 128 + _s0);    \
    }                                                                        \
} while (0)

#define READBL(Br_, kt_) do {                                                \
    _Pragma("unroll")                                                        \
    for (int _q = 0; _q < 11; ++_q) {                                        \
        int _r = lr + (kt_) + _q * 16;                                       \
        int _s0 = (g ^ (_r & 7)) << 4;                                       \
        bL[_q] = *reinterpret_cast<const i32x4*>((Br_) + _r * 128 + (_s0 ^ 64)); \
    }                                                                        \
} while (0)

// bH products (accH += a0*bH, accM += a1*bH): 64 MFMAs, 8-acc reuse distance.
#define COMPH(a_) do {                                                       \
    _Pragma("unroll")                                                        \
    for (int _kb = 0; _kb < 4; ++_kb)                                        \
    { _Pragma("unroll")                                                      \
      for (int _cf = 0; _cf < 8; ++_cf)                                      \
        asm volatile("v_mfma_i32_16x16x64_i8 %0, %1, %2, %0"                 \
            : "+v"(accH[_cf]) : "v"(a_[_kb*2+0]), "v"(bH[_cf+_kb])); }       \
    _Pragma("unroll")                                                        \
    for (int _kb = 0; _kb < 4; ++_kb)                                        \
    { _Pragma("unroll")                                                      \
      for (int _cf = 0; _cf < 8; ++_cf)                                      \
        asm volatile("v_mfma_i32_16x16x64_i8 %0, %1, %2, %0"                 \
            : "+v"(accM[_cf]) : "v"(a_[_kb*2+1]), "v"(bH[_cf+_kb])); }       \
} while (0)

// bL product (accM += a0*bL): 32 MFMAs.
#define COMPL(a_) do {                                                       \
    _Pragma("unroll")                                                        \
    for (int _kb = 0; _kb < 4; ++_kb)                                        \
    { _Pragma("unroll")                                                      \
      for (int _cf = 0; _cf < 8; ++_cf)                                      \
        asm volatile("v_mfma_i32_16x16x64_i8 %0, %1, %2, %0"                 \
            : "+v"(accM[_cf]) : "v"(a_[_kb*2+0]), "v"(bL[_cf+_kb])); }       \
} while (0)

#define SLOAD(c_) do {                                                       \
    _Pragma("unroll")                                                        \
    for (int _s = 0; _s < 6; ++_s) {                                         \
        int _u = _s * 256 + tid;                                             \
        int _row = _u >> 3, _un = _u & 7;                                    \
        stg[_s] = *reinterpret_cast<const i32x4*>(                           \
            xt + (size_t)(l0 + _row) * 512 + (c_) * 128 + _un * 16);         \
    }                                                                        \
} while (0)

#define SWRITE(buf_) do {                                                    \
    _Pragma("unroll")                                                        \
    for (int _s = 0; _s < 6; ++_s) {                                         \
        int _u = _s * 256 + tid;                                             \
        int _row = _u >> 3, _un = _u & 7;                                    \
        *reinterpret_cast<i32x4*>((buf_) + _row * 128 +                      \
            ((_un ^ (_row & 7)) << 4)) = stg[_s];                            \
    }                                                                        \
} while (0)

__global__ __launch_bounds__(256, 2)
void conv_i8(const char* __restrict__ aw, const char* __restrict__ xt,
             const float* __restrict__ bias, float* __restrict__ y)
{
    __shared__ char Bs[2][192 * 128];   // 48 KB total

    const int tid  = threadIdx.x;
    const int lane = tid & 63;
    const int wv   = tid >> 6;
    const int id   = blockIdx.x;            // 0..511
    const int og   = (id & 7) >> 1;         // XCD-locality: 2 MB A slice per XCD L2
    const int lblk = (id >> 3) * 2 + (id & 1);
    const int l0   = lblk * 128;
    const int lr   = lane & 15;
    const int g    = lane >> 4;

    i32x4 accH[8], accM[8];
#pragma unroll
    for (int i = 0; i < 8; ++i) {
        accH[i] = (i32x4){0, 0, 0, 0};
        accM[i] = (i32x4){0, 0, 0, 0};
    }

    const char* Abase = aw + (size_t)(og * 4 + wv) * 524288 + lr * 64 + g * 16;

    i32x4 aP[8], aQ[8], stg[6];
    i32x4 bH[11], bL[11];

    SLOAD(0);
    PREFI(aP, 0, 0);
    SWRITE(Bs[0]);
    __syncthreads();

    for (int c = 0; c < 4; ++c) {
        if (c < 3) SLOAD(c + 1);
        char* Br = Bs[c & 1];

        for (int ktt = 0; ktt < 16; ktt += 2) {
            PREFI(aQ, c, ktt + 1);
            READBH(Br, ktt);
            READBL(Br, ktt);
            COMPH(aP);
            COMPL(aP);
            if (ktt < 14)      PREFI(aP, c, ktt + 2);
            else if (c < 3)    PREFI(aP, c + 1, 0);
            READBH(Br, ktt + 1);
            READBL(Br, ktt + 1);
            COMPH(aQ);
            COMPL(aQ);
        }

        if (c < 3) {
            SWRITE(Bs[(c + 1) & 1]);
            __syncthreads();
        }
    }

    asm volatile("s_nop 7\n\ts_nop 7" :::);   // MFMA -> VALU hazard guard

    const int obase = og * 64 + wv * 16 + g * 4;
#pragma unroll
    for (int r = 0; r < 4; ++r) {
        int o = obase + r;
        float bv = bias[o];
#pragma unroll
        for (int cf = 0; cf < 8; ++cf) {
            int ll = l0 + cf * 16 + lr;
            if (ll < LOUT) {
                int hA = accH[cf][r];
                int hi = hA >> 12;          // hA = hi*4096 + lo, both exact in f32
                int lo = hA & 4095;
                float v = (float)hi * 0.5f
                        + (float)lo * (1.f / 8192.f)
                        + (float)accM[cf][r] * (1.f / 2097152.f)
                        + bv;
                y[(size_t)o * LOUT + ll] = v;
            }
        }
    }
}

// ---- chunked-parallel tanh scan ----
#define CHUNK 64
#define WARM 32
#define NCHUNK 256

static __device__ __forceinline__ float fast_tanh(float z) {
    float e = __expf(2.f * z);
    return 1.f - 2.f / (e + 1.f);
}

__global__ void scan_kernel(const float* __restrict__ y,
                            const float* __restrict__ pw,
                            float* __restrict__ out)
{
    int t = blockIdx.x * blockDim.x + threadIdx.x;   // 256*256
    int m = t >> 8;
    int c = t & (NCHUNK - 1);
    float w = pw[m];
    const float* ym = y + (size_t)m * LOUT;
    float* om = out + (size_t)m * (LOUT + 1);
    float pos;
    int l;
    if (c == 0) {
        om[0] = -1.f;
        pos = -1.f;
        l = 0;
    } else {
        pos = 0.f;
        l = c * CHUNK - WARM;
        int s = c * CHUNK;
#pragma unroll 4
        for (; l < s; ++l)
            pos = fast_tanh(fmaf(pos, w, ym[l]));
    }
    int e = min((c + 1) * CHUNK, LOUT);
#pragma unroll 4
    for (; l < e; ++l) {
        pos = fast_tanh(fmaf(pos, w, ym[l]));
        om[l + 1] = pos;
    }
}

extern "C" void kernel_launch(void* const* d_in, const int* in_sizes, int n_in,
                              void* d_out, int out_size, void* d_ws, size_t ws_size,
                              hipStream_t stream) {
    const float* x  = (const float*)d_in[0];
    const float* cw = (const float*)d_in[1];
    const float* cb = (const float*)d_in[2];
    const float* pw = (const float*)d_in[3];
    float* out = (float*)d_out;

    float* y  = (float*)d_ws;
    char*  aw = (char*)d_ws + Y_BYTES;
    char*  xt = (char*)d_ws + Y_BYTES + AW_I8;

    quant_fused<<<1540, 256, 0, stream>>>(cw, x, aw, xt);
    conv_i8<<<512, 256, 0, stream>>>(aw, xt, cb, y);
    scan_kernel<<<256, 256, 0, stream>>>(y, pw, out);
}